// Round 11
// baseline (112.201 us; speedup 1.0000x reference)
//
#include <hip/hip_runtime.h>
#include <hip/hip_bf16.h>

// SNDE: 100-step Euler of  u += (tanh(u@W1+b1)@W2 + b2 - gamma*th*pinv*(1-th^2)*wg) * dt
// 256 blocks x 8 waves (512 thr) x 16 samples; bf16 MFMA 16x16x32.
// R10 = R9 + (1) 4-bit row swizzle SWZ(r)=((r&7)<<4)|((r&8)<<3) on uAs+hp:
// previous 3-bit swizzle left rows r and r+8 on the same bank -> 2-way conflict
// in every quarter-wave of the b128 reads (measured 128 cyc/step); (2) coefs
// read issued before the A2 burst; (3) tanh via exp2f (one fused multiply).

#define GAMMA 0.1f
#define EPSG  1e-12f

typedef __attribute__((ext_vector_type(8))) short bf16x8;
typedef __attribute__((ext_vector_type(4))) float f32x4;

// byte-offset XOR swizzle: distinct bank set for all 16 rows (quarter-wave clean)
#define SWZ(r) (((((unsigned)(r)) & 7u) << 4) | ((((unsigned)(r)) & 8u) << 3))

__device__ __forceinline__ float ftanh(float x) {
    // tanh(x) = 1 - 2/(2^(x*2*log2e)+1); exp2 is the native v_exp_f32
    float e = exp2f(x * 2.8853900817779268f);
    return 1.0f - 2.0f * __builtin_amdgcn_rcpf(e + 1.0f);
}

__device__ __forceinline__ unsigned int f2bf(float f) {
    unsigned int u = __float_as_uint(f);
    return (u + 0x7fffu + ((u >> 16) & 1u)) >> 16;
}

// packed (lo,hi) f32 -> (bf16 lo | bf16 hi << 16), RNE; compiler emits cvt_pk
__device__ __forceinline__ unsigned int pack2(float lo, float hi) {
    union { __hip_bfloat162 h; unsigned int u; } cv;
    cv.h = __float22bfloat162_rn(float2{lo, hi});
    return cv.u;
}

// LDS-only barrier: order LDS ops without draining vmcnt (out stores float).
#define BARRIER_LGKM() asm volatile("s_waitcnt lgkmcnt(0)\ns_barrier" ::: "memory")

// k-slot permutation for the packed-pair h layout (pairs (c, c+16) per 32-block):
// applied identically to A2 reads and B2 init, so it cancels.
__device__ __forceinline__ int kperm(int lg, int j) {
    return lg * 4 + (j >> 1) + ((j & 1) << 4);
}

__global__ __launch_bounds__(512, 1) void snde_kernel(
    const float* __restrict__ y0, const float* __restrict__ t,
    const float* __restrict__ W1, const float* __restrict__ b1,
    const float* __restrict__ W2, const float* __restrict__ b2,
    const float* __restrict__ wg, const float* __restrict__ bgp,
    float* __restrict__ out)
{
    __shared__ unsigned short uAs[16 * 64];   // bf16 u tile, natural layout, swizzled (2 KB)
    __shared__ unsigned int   hp[16 * 128];   // packed bf16-pair h tile, swizzled (8 KB)
    __shared__ float          coefs[16];      // per-sample stabilization coef

    const int tid = threadIdx.x;
    const int w   = tid >> 6;   // wave 0..7
    const int l   = tid & 63;
    const int l15 = l & 15;
    const int lg  = l >> 4;
    const int nt  = w & 3;      // GEMM2 output tile (cols 16nt..16nt+15), waves 0-3
    const int s0g = blockIdx.x * 16;

    // ---------------- weight fragments -> registers (one-time) ----------------
    // GEMM1: h(16x256) = u(16x64) @ W1. Wave w owns n in [32w, 32w+32); natural k.
    bf16x8 B1[2][2];
    #pragma unroll
    for (int ntt = 0; ntt < 2; ++ntt) {
        const int n = w * 32 + ntt * 16 + l15;
        #pragma unroll
        for (int kt = 0; kt < 2; ++kt) {
            bf16x8 v;
            #pragma unroll
            for (int j = 0; j < 8; ++j)
                v[j] = (short)f2bf(W1[(kt * 32 + lg * 8 + j) * 256 + n]);
            B1[ntt][kt] = v;
        }
    }
    // GEMM2: f(16x64) = h(16x256) @ W2. Tile nt, FULL K=256; kperm'd k-order.
    bf16x8 B2[8];
    #pragma unroll
    for (int kt = 0; kt < 8; ++kt) {
        const int n = nt * 16 + l15;
        bf16x8 v;
        #pragma unroll
        for (int j = 0; j < 8; ++j)
            v[j] = (short)f2bf(W2[(kt * 32 + kperm(lg, j)) * 64 + n]);
        B2[kt] = v;
    }
    // z-column frags (wave 4): wg in column 0, natural k (uses A1)
    bf16x8 Bz[2];
    #pragma unroll
    for (int kt = 0; kt < 2; ++kt) {
        bf16x8 v;
        #pragma unroll
        for (int j = 0; j < 8; ++j)
            v[j] = (l15 == 0) ? (short)f2bf(wg[kt * 32 + lg * 8 + j]) : (short)0;
        Bz[kt] = v;
    }

    float b1v[2];
    #pragma unroll
    for (int ntt = 0; ntt < 2; ++ntt) b1v[ntt] = b1[w * 32 + ntt * 16 + l15];
    const float b2v = b2[nt * 16 + l15];     // seeds accA (same for all 4 rows)
    const float wgv = wg[nt * 16 + l15];
    float wsum = wg[l] * wg[l];
    #pragma unroll
    for (int m = 1; m < 64; m <<= 1) wsum += __shfl_xor(wsum, m, 64);
    const float bg  = bgp[0];
    const float dtv = t[1] - t[0];

    // ---------------- init: uold regs + uAs (natural, swizzled) + out[0] ----------------
    float uold[4];
    if (w < 4) {
        #pragma unroll
        for (int i = 0; i < 4; ++i) {
            const int s = lg * 4 + i;
            const int c = nt * 16 + l15;
            uold[i] = y0[(size_t)(s0g + s) * 64 + c];
            unsigned int boff = ((unsigned)(s * 128 + c * 2)) ^ SWZ(s);
            *(unsigned short*)((char*)uAs + boff) = (unsigned short)f2bf(uold[i]);
            out[(size_t)(s0g + s) * 64 + c] = uold[i];
        }
    }
    __syncthreads();

    for (int step = 0; step < 100; ++step) {
        // ======== phase A: GEMM1 + tanh + packed h publish (+ z/coef on wave 4) ========
        bf16x8 A1[2];
        #pragma unroll
        for (int kt = 0; kt < 2; ++kt) {
            unsigned int boff = ((unsigned)(l15 * 128 + (kt * 32 + lg * 8) * 2)) ^ SWZ(l15);
            A1[kt] = *(const bf16x8*)((const char*)uAs + boff);
        }
        f32x4 acc1[2];
        #pragma unroll
        for (int ntt = 0; ntt < 2; ++ntt) {
            acc1[ntt][0] = b1v[ntt]; acc1[ntt][1] = b1v[ntt];
            acc1[ntt][2] = b1v[ntt]; acc1[ntt][3] = b1v[ntt];
        }
        #pragma unroll
        for (int ntt = 0; ntt < 2; ++ntt)
            #pragma unroll
            for (int kt = 0; kt < 2; ++kt)
                acc1[ntt] = __builtin_amdgcn_mfma_f32_16x16x32_bf16(A1[kt], B1[ntt][kt], acc1[ntt], 0, 0, 0);

        if (w == 4) {   // z = u.wg per sample -> coef chain -> coefs[16]
            f32x4 accz = {0.f, 0.f, 0.f, 0.f};
            #pragma unroll
            for (int kt = 0; kt < 2; ++kt)
                accz = __builtin_amdgcn_mfma_f32_16x16x32_bf16(A1[kt], Bz[kt], accz, 0, 0, 0);
            if (l15 == 0) {
                f32x4 cf;
                #pragma unroll
                for (int i = 0; i < 4; ++i) {
                    const float th = ftanh(accz[i] + bg);
                    const float qq = 1.0f - th * th;
                    const float sg = qq * qq * wsum;
                    const float pinv = (fabsf(sg) > EPSG) ? __builtin_amdgcn_rcpf(sg) : 0.0f;
                    cf[i] = GAMMA * th * pinv * qq;
                }
                *(f32x4*)(&coefs[lg * 4]) = cf;
            }
        }

        // packed h scatter: word (row m, w*16+l15) = (h[m][32w+l15], h[m][32w+16+l15])
        #pragma unroll
        for (int i = 0; i < 4; ++i) {
            const int m = lg * 4 + i;
            const unsigned int pk = pack2(ftanh(acc1[0][i]), ftanh(acc1[1][i]));
            unsigned int boff = ((unsigned)(m * 512 + (w * 16 + l15) * 4)) ^ SWZ(m);
            *(unsigned int*)((char*)hp + boff) = pk;
        }
        BARRIER_LGKM();   // h + coefs visible to all waves

        // ======== phase B (waves 0-3 only): full-K GEMM2 -> in-lane update ========
        if (w < 4) {
            // coefs first: ready at barrier 1, latency hides under the A2 burst
            const f32x4 cf = *(const f32x4*)(&coefs[lg * 4]);
            bf16x8 A2[8];
            #pragma unroll
            for (int kt = 0; kt < 8; ++kt) {
                unsigned int boff = ((unsigned)(l15 * 512 + (kt * 16 + lg * 4) * 4)) ^ SWZ(l15);
                A2[kt] = *(const bf16x8*)((const char*)hp + boff);
            }
            // 4 independent 2-deep accumulator chains
            f32x4 accA, accB, accC, accD;
            accA[0] = b2v; accA[1] = b2v; accA[2] = b2v; accA[3] = b2v;
            accB[0] = 0.f; accB[1] = 0.f; accB[2] = 0.f; accB[3] = 0.f;
            accC = accB; accD = accB;
            accA = __builtin_amdgcn_mfma_f32_16x16x32_bf16(A2[0], B2[0], accA, 0, 0, 0);
            accB = __builtin_amdgcn_mfma_f32_16x16x32_bf16(A2[1], B2[1], accB, 0, 0, 0);
            accC = __builtin_amdgcn_mfma_f32_16x16x32_bf16(A2[2], B2[2], accC, 0, 0, 0);
            accD = __builtin_amdgcn_mfma_f32_16x16x32_bf16(A2[3], B2[3], accD, 0, 0, 0);
            accA = __builtin_amdgcn_mfma_f32_16x16x32_bf16(A2[4], B2[4], accA, 0, 0, 0);
            accB = __builtin_amdgcn_mfma_f32_16x16x32_bf16(A2[5], B2[5], accB, 0, 0, 0);
            accC = __builtin_amdgcn_mfma_f32_16x16x32_bf16(A2[6], B2[6], accC, 0, 0, 0);
            accD = __builtin_amdgcn_mfma_f32_16x16x32_bf16(A2[7], B2[7], accD, 0, 0, 0);

            const int c = nt * 16 + l15;
            float* orow = &out[(size_t)(step + 1) * (4096 * 64) + (size_t)(s0g + lg * 4) * 64 + c];
            #pragma unroll
            for (int i = 0; i < 4; ++i) {
                const float f  = (accA[i] + accB[i]) + (accC[i] + accD[i]);
                const float un = uold[i] + (f - cf[i] * wgv) * dtv;
                uold[i] = un;
                const int s = lg * 4 + i;
                unsigned int boff = ((unsigned)(s * 128 + c * 2)) ^ SWZ(s);
                *(unsigned short*)((char*)uAs + boff) = (unsigned short)f2bf(un);
                orow[i * 64] = un;
            }
        }
        BARRIER_LGKM();   // uAs republished
    }
}

extern "C" void kernel_launch(void* const* d_in, const int* in_sizes, int n_in,
                              void* d_out, int out_size, void* d_ws, size_t ws_size,
                              hipStream_t stream) {
    const float* y0 = (const float*)d_in[0];
    const float* t  = (const float*)d_in[1];
    const float* W1 = (const float*)d_in[2];
    const float* b1 = (const float*)d_in[3];
    const float* W2 = (const float*)d_in[4];
    const float* b2 = (const float*)d_in[5];
    const float* wg = (const float*)d_in[6];
    const float* bg = (const float*)d_in[7];
    float* out = (float*)d_out;

    snde_kernel<<<dim3(256), dim3(512), 0, stream>>>(y0, t, W1, b1, W2, b2, wg, bg, out);
}

// Round 12
// 93.168 us; speedup vs baseline: 1.2043x; 1.2043x over previous
//
#include <hip/hip_runtime.h>
#include <hip/hip_bf16.h>

// SNDE: 100-step Euler of  u += (tanh(u@W1+b1)@W2 + b2 - gamma*th*pinv*(1-th^2)*wg) * dt
// 256 blocks x 8 waves (512 thr) x 16 samples; bf16 MFMA 16x16x32.
// R11 = R9 (best: 94.2us) + ONE change: the per-sample stabilization coef chain
// moves from wave 4's phase-A tail (serial, on the barrier-1 critical path) to
// waves 0-3 at the start of phase B, where it overlaps the A2 ds_read latency
// and waves 4-7 are idle. Wave 4 now publishes only zs[16] = u.wg (raw MFMA out).
// R10's 4-bit swizzle (tripled bank conflicts) and exp2f (OCML fixup VALU) reverted.

#define GAMMA 0.1f
#define EPSG  1e-12f

typedef __attribute__((ext_vector_type(8))) short bf16x8;
typedef __attribute__((ext_vector_type(4))) float f32x4;

__device__ __forceinline__ float ftanh(float x) {
    float e = __expf(2.0f * x);
    return 1.0f - 2.0f * __builtin_amdgcn_rcpf(e + 1.0f);
}

__device__ __forceinline__ unsigned int f2bf(float f) {
    unsigned int u = __float_as_uint(f);
    return (u + 0x7fffu + ((u >> 16) & 1u)) >> 16;
}

// packed (lo,hi) f32 -> (bf16 lo | bf16 hi << 16), RNE; compiler emits cvt_pk
__device__ __forceinline__ unsigned int pack2(float lo, float hi) {
    union { __hip_bfloat162 h; unsigned int u; } cv;
    cv.h = __float22bfloat162_rn(float2{lo, hi});
    return cv.u;
}

// LDS-only barrier: order LDS ops without draining vmcnt (out stores float).
#define BARRIER_LGKM() asm volatile("s_waitcnt lgkmcnt(0)\ns_barrier" ::: "memory")

// k-slot permutation for the packed-pair h layout (pairs (c, c+16) per 32-block):
// applied identically to A2 reads and B2 init, so it cancels.
__device__ __forceinline__ int kperm(int lg, int j) {
    return lg * 4 + (j >> 1) + ((j & 1) << 4);
}

__global__ __launch_bounds__(512, 1) void snde_kernel(
    const float* __restrict__ y0, const float* __restrict__ t,
    const float* __restrict__ W1, const float* __restrict__ b1,
    const float* __restrict__ W2, const float* __restrict__ b2,
    const float* __restrict__ wg, const float* __restrict__ bgp,
    float* __restrict__ out)
{
    __shared__ unsigned short uAs[16 * 64];        // bf16 u tile, swizzled (2 KB)
    __shared__ unsigned int   hp[16 * 128];        // packed bf16-pair h tile, swizzled (8 KB)
    __shared__ __align__(16) float zs[16];         // zp = u.wg per sample (raw)

    const int tid = threadIdx.x;
    const int w   = tid >> 6;   // wave 0..7
    const int l   = tid & 63;
    const int l15 = l & 15;
    const int lg  = l >> 4;
    const int nt  = w & 3;      // GEMM2 output tile (cols 16nt..16nt+15), waves 0-3
    const int s0g = blockIdx.x * 16;

    // ---------------- weight fragments -> registers (one-time) ----------------
    // GEMM1: h(16x256) = u(16x64) @ W1. Wave w owns n in [32w, 32w+32); natural k.
    bf16x8 B1[2][2];
    #pragma unroll
    for (int ntt = 0; ntt < 2; ++ntt) {
        const int n = w * 32 + ntt * 16 + l15;
        #pragma unroll
        for (int kt = 0; kt < 2; ++kt) {
            bf16x8 v;
            #pragma unroll
            for (int j = 0; j < 8; ++j)
                v[j] = (short)f2bf(W1[(kt * 32 + lg * 8 + j) * 256 + n]);
            B1[ntt][kt] = v;
        }
    }
    // GEMM2: f(16x64) = h(16x256) @ W2. Tile nt, FULL K=256; kperm'd k-order.
    bf16x8 B2[8];
    #pragma unroll
    for (int kt = 0; kt < 8; ++kt) {
        const int n = nt * 16 + l15;
        bf16x8 v;
        #pragma unroll
        for (int j = 0; j < 8; ++j)
            v[j] = (short)f2bf(W2[(kt * 32 + kperm(lg, j)) * 64 + n]);
        B2[kt] = v;
    }
    // z-column frags (wave 4): wg in column 0, natural k (uses A1)
    bf16x8 Bz[2];
    #pragma unroll
    for (int kt = 0; kt < 2; ++kt) {
        bf16x8 v;
        #pragma unroll
        for (int j = 0; j < 8; ++j)
            v[j] = (l15 == 0) ? (short)f2bf(wg[kt * 32 + lg * 8 + j]) : (short)0;
        Bz[kt] = v;
    }

    float b1v[2];
    #pragma unroll
    for (int ntt = 0; ntt < 2; ++ntt) b1v[ntt] = b1[w * 32 + ntt * 16 + l15];
    const float b2v = b2[nt * 16 + l15];     // seeds accA (same for all 4 rows)
    const float wgv = wg[nt * 16 + l15];
    float wsum = wg[l] * wg[l];
    #pragma unroll
    for (int m = 1; m < 64; m <<= 1) wsum += __shfl_xor(wsum, m, 64);
    const float bg  = bgp[0];
    const float dtv = t[1] - t[0];

    // ---------------- init: uold regs + uAs (natural, swizzled) + out[0] ----------------
    float uold[4];
    if (w < 4) {
        #pragma unroll
        for (int i = 0; i < 4; ++i) {
            const int s = lg * 4 + i;
            const int c = nt * 16 + l15;
            uold[i] = y0[(size_t)(s0g + s) * 64 + c];
            unsigned int boff = ((unsigned)(s * 128 + c * 2)) ^ (((unsigned)(s & 7)) << 4);
            *(unsigned short*)((char*)uAs + boff) = (unsigned short)f2bf(uold[i]);
            out[(size_t)(s0g + s) * 64 + c] = uold[i];
        }
    }
    __syncthreads();

    for (int step = 0; step < 100; ++step) {
        // ======== phase A: GEMM1 + tanh + packed h publish (+ raw z on wave 4) ========
        bf16x8 A1[2];
        #pragma unroll
        for (int kt = 0; kt < 2; ++kt) {
            unsigned int boff = ((unsigned)(l15 * 128 + (kt * 32 + lg * 8) * 2))
                              ^ (((unsigned)(l15 & 7)) << 4);
            A1[kt] = *(const bf16x8*)((const char*)uAs + boff);
        }
        f32x4 acc1[2];
        #pragma unroll
        for (int ntt = 0; ntt < 2; ++ntt) {
            acc1[ntt][0] = b1v[ntt]; acc1[ntt][1] = b1v[ntt];
            acc1[ntt][2] = b1v[ntt]; acc1[ntt][3] = b1v[ntt];
        }
        #pragma unroll
        for (int ntt = 0; ntt < 2; ++ntt)
            #pragma unroll
            for (int kt = 0; kt < 2; ++kt)
                acc1[ntt] = __builtin_amdgcn_mfma_f32_16x16x32_bf16(A1[kt], B1[ntt][kt], acc1[ntt], 0, 0, 0);

        if (w == 4) {   // zs = u.wg per sample (raw MFMA column; no coef math here)
            f32x4 accz = {0.f, 0.f, 0.f, 0.f};
            #pragma unroll
            for (int kt = 0; kt < 2; ++kt)
                accz = __builtin_amdgcn_mfma_f32_16x16x32_bf16(A1[kt], Bz[kt], accz, 0, 0, 0);
            if (l15 == 0) *(f32x4*)(&zs[lg * 4]) = accz;
        }

        // packed h scatter: word (row m, w*16+l15) = (h[m][32w+l15], h[m][32w+16+l15])
        #pragma unroll
        for (int i = 0; i < 4; ++i) {
            const int m = lg * 4 + i;
            const unsigned int pk = pack2(ftanh(acc1[0][i]), ftanh(acc1[1][i]));
            unsigned int boff = ((unsigned)(m * 512 + (w * 16 + l15) * 4))
                              ^ (((unsigned)(m & 7)) << 4);
            *(unsigned int*)((char*)hp + boff) = pk;
        }
        BARRIER_LGKM();   // h + zs visible to all waves

        // ======== phase B (waves 0-3 only): full-K GEMM2 -> in-lane update ========
        if (w < 4) {
            // zs read issued first (1 lgkm op, lands before the A2 burst);
            // coef chains below overlap the A2 ds_read latency (waves 4-7 idle).
            const f32x4 z4 = *(const f32x4*)(&zs[lg * 4]);
            bf16x8 A2[8];
            #pragma unroll
            for (int kt = 0; kt < 8; ++kt) {
                unsigned int boff = ((unsigned)(l15 * 512 + (kt * 16 + lg * 4) * 4))
                                  ^ (((unsigned)(l15 & 7)) << 4);
                A2[kt] = *(const bf16x8*)((const char*)hp + boff);
            }
            // per-lane coef chains for this lane's 4 samples (overlaps A2 latency)
            f32x4 cf;
            #pragma unroll
            for (int i = 0; i < 4; ++i) {
                const float th = ftanh(z4[i] + bg);
                const float qq = 1.0f - th * th;
                const float sg = qq * qq * wsum;
                const float pinv = (fabsf(sg) > EPSG) ? __builtin_amdgcn_rcpf(sg) : 0.0f;
                cf[i] = GAMMA * th * pinv * qq;
            }
            // 4 independent 2-deep accumulator chains
            f32x4 accA, accB, accC, accD;
            accA[0] = b2v; accA[1] = b2v; accA[2] = b2v; accA[3] = b2v;
            accB[0] = 0.f; accB[1] = 0.f; accB[2] = 0.f; accB[3] = 0.f;
            accC = accB; accD = accB;
            accA = __builtin_amdgcn_mfma_f32_16x16x32_bf16(A2[0], B2[0], accA, 0, 0, 0);
            accB = __builtin_amdgcn_mfma_f32_16x16x32_bf16(A2[1], B2[1], accB, 0, 0, 0);
            accC = __builtin_amdgcn_mfma_f32_16x16x32_bf16(A2[2], B2[2], accC, 0, 0, 0);
            accD = __builtin_amdgcn_mfma_f32_16x16x32_bf16(A2[3], B2[3], accD, 0, 0, 0);
            accA = __builtin_amdgcn_mfma_f32_16x16x32_bf16(A2[4], B2[4], accA, 0, 0, 0);
            accB = __builtin_amdgcn_mfma_f32_16x16x32_bf16(A2[5], B2[5], accB, 0, 0, 0);
            accC = __builtin_amdgcn_mfma_f32_16x16x32_bf16(A2[6], B2[6], accC, 0, 0, 0);
            accD = __builtin_amdgcn_mfma_f32_16x16x32_bf16(A2[7], B2[7], accD, 0, 0, 0);

            const int c = nt * 16 + l15;
            float* orow = &out[(size_t)(step + 1) * (4096 * 64) + (size_t)(s0g + lg * 4) * 64 + c];
            #pragma unroll
            for (int i = 0; i < 4; ++i) {
                const float f  = (accA[i] + accB[i]) + (accC[i] + accD[i]);
                const float un = uold[i] + (f - cf[i] * wgv) * dtv;
                uold[i] = un;
                const int s = lg * 4 + i;
                unsigned int boff = ((unsigned)(s * 128 + c * 2)) ^ (((unsigned)(s & 7)) << 4);
                *(unsigned short*)((char*)uAs + boff) = (unsigned short)f2bf(un);
                orow[i * 64] = un;
            }
        }
        BARRIER_LGKM();   // uAs republished
    }
}

extern "C" void kernel_launch(void* const* d_in, const int* in_sizes, int n_in,
                              void* d_out, int out_size, void* d_ws, size_t ws_size,
                              hipStream_t stream) {
    const float* y0 = (const float*)d_in[0];
    const float* t  = (const float*)d_in[1];
    const float* W1 = (const float*)d_in[2];
    const float* b1 = (const float*)d_in[3];
    const float* W2 = (const float*)d_in[4];
    const float* b2 = (const float*)d_in[5];
    const float* wg = (const float*)d_in[6];
    const float* bg = (const float*)d_in[7];
    float* out = (float*)d_out;

    snde_kernel<<<dim3(256), dim3(512), 0, stream>>>(y0, t, W1, b1, W2, b2, wg, bg, out);
}